// Round 2
// baseline (2142.411 us; speedup 1.0000x reference)
//
#include <hip/hip_runtime.h>
#include <stdint.h>
#include <stddef.h>

#define BB 8
#define TENC 200
#define UU 100
#define UP1 101
#define VP1 1025
#define ED 128
#define PD 512
#define LSTM_NWG 64

typedef __attribute__((ext_vector_type(8))) unsigned short ushort8;
typedef __attribute__((ext_vector_type(8))) __bf16 bf16x8;
typedef __attribute__((ext_vector_type(4))) float f32x4;

__device__ __forceinline__ float bf2f(unsigned short u){
  unsigned int x = ((unsigned int)u) << 16;
  return __builtin_bit_cast(float, x);
}
__device__ __forceinline__ unsigned short f2bf(float f){
  unsigned int x = __builtin_bit_cast(unsigned int, f);
  unsigned int r = (x + 0x7fffu + ((x >> 16) & 1u)) >> 16;
  return (unsigned short)r;
}
__device__ __forceinline__ float tanh_fast(float x){
  float e = __expf(2.0f * x);
  return 1.0f - 2.0f / (e + 1.0f);
}
__device__ __forceinline__ float sigm(float x){
  return 1.0f / (1.0f + __expf(-x));
}
__device__ __forceinline__ void gload_lds16(const unsigned short* gsrc, unsigned short* ldst){
  __builtin_amdgcn_global_load_lds((const __attribute__((address_space(1))) void*)gsrc,
                                   (__attribute__((address_space(3))) void*)ldst, 16, 0, 0);
}

// ---------------- fp32 -> bf16 convert (W_joint) ----------------
__global__ __launch_bounds__(256) void k_cvt_bf16(const float* __restrict__ src,
                                                  unsigned short* __restrict__ dst, int n){
  int i = blockIdx.x * 256 + threadIdx.x;
  if (i < n) dst[i] = f2bf(src[i]);
}

// ---------------- K1: embedding + x-part of LSTM gates ----------------
__global__ __launch_bounds__(256) void k_xgate(
    const float* __restrict__ emb, const int* __restrict__ targets,
    const float* __restrict__ W_ih, const float* __restrict__ b_ih,
    const float* __restrict__ b_hh, float* __restrict__ xg)
{
  __shared__ float e_s[BB * ED];
  const int u  = blockIdx.x >> 2;
  const int jq = blockIdx.x & 3;
  const int tid = threadIdx.x;
  for (int idx = tid; idx < BB * ED; idx += 256){
    int b = idx >> 7, e = idx & 127;
    int tok = (u == 0) ? 1024 : targets[b * UU + (u - 1)];
    e_s[idx] = emb[(size_t)tok * ED + e];
  }
  __syncthreads();
  float acc[2][BB];
  #pragma unroll
  for (int r = 0; r < 2; r++)
    #pragma unroll
    for (int b = 0; b < BB; b++) acc[r][b] = 0.0f;
  const int j0 = jq * 512 + tid;
  const float* w0p = W_ih + (size_t)j0 * ED;
  const float* w1p = W_ih + (size_t)(j0 + 256) * ED;
  for (int e = 0; e < ED; e++){
    float w0 = w0p[e], w1 = w1p[e];
    #pragma unroll
    for (int b = 0; b < BB; b++){
      float ev = e_s[b * ED + e];
      acc[0][b] = fmaf(ev, w0, acc[0][b]);
      acc[1][b] = fmaf(ev, w1, acc[1][b]);
    }
  }
  #pragma unroll
  for (int r = 0; r < 2; r++){
    int j = j0 + r * 256;
    float bias = b_ih[j] + b_hh[j];
    #pragma unroll
    for (int b = 0; b < BB; b++)
      xg[((size_t)b * UP1 + u) * 2048 + j] = acc[r][b] + bias;
  }
}

// ---------------- K2: persistent LSTM (all 101 steps, one launch) ----------------
// 64 WGs x 256 thr, 1 WG/CU (84KB LDS). WG wg owns hidden units [8*wg, 8*wg+8).
// Spin barrier on cnt[u] (memset to 0 each launch).
__global__ __launch_bounds__(256) void k_lstm_all(
    const float* __restrict__ xg, const float* __restrict__ W_hh,
    float* __restrict__ pred, unsigned int* __restrict__ cnt)
{
  __shared__ float W_s[32][516];   // 66 KB: 32 gate-rows x 512
  __shared__ float h_s[8][520];    // 16.6 KB
  __shared__ float sums[32][9];
  const int tid = threadIdx.x;
  const int wg  = blockIdx.x;
  const int p0  = wg * 8;
  // stage W_hh rows: jl -> global row (jl>>3)*512 + p0 + (jl&7)
  {
    int r = tid >> 3, c0 = tid & 7;
    int grow = (r >> 3) * PD + p0 + (r & 7);
    const float* src = W_hh + (size_t)grow * PD;
    for (int c = c0; c < 128; c += 8)
      *(float4*)&W_s[r][c * 4] = *(const float4*)(src + c * 4);
  }
  const int jl = tid >> 3, bl = tid & 7;
  float c_reg = 0.0f;               // cell state, live in tid<64 threads
  __syncthreads();
  for (int u = 0; u < UP1; u++){
    // prefetch x-gates early (independent of h)
    float xi = 0.f, xf = 0.f, xgv = 0.f, xo = 0.f;
    if (tid < 64){
      int pl = tid >> 3, b = tid & 7;
      const float* xr = xg + ((size_t)(b * UP1 + u)) * 2048;
      int p = p0 + pl;
      xi = xr[p]; xf = xr[512 + p]; xgv = xr[1024 + p]; xo = xr[1536 + p];
    }
    // load h_{u-1}
    if (u > 0){
      int b2 = tid >> 5;
      int k0 = (tid & 31) * 4;
      const float* hp = pred + ((size_t)(b2 * UP1 + (u - 1))) * PD;
      #pragma unroll
      for (int rr = 0; rr < 4; rr++)
        *(float4*)&h_s[b2][k0 + rr * 128] = *(const float4*)(hp + k0 + rr * 128);
    } else {
      for (int i = tid; i < 8 * PD; i += 256) h_s[i >> 9][i & 511] = 0.0f;
    }
    __syncthreads();
    float acc = 0.0f;
    #pragma unroll 8
    for (int k = 0; k < PD; k += 4){
      float4 wv = *(const float4*)&W_s[jl][k];
      float4 hv = *(const float4*)&h_s[bl][k];
      acc = fmaf(wv.x, hv.x, acc); acc = fmaf(wv.y, hv.y, acc);
      acc = fmaf(wv.z, hv.z, acc); acc = fmaf(wv.w, hv.w, acc);
    }
    sums[jl][bl] = acc;
    __syncthreads();
    if (tid < 64){
      int pl = tid >> 3, b = tid & 7;
      int p = p0 + pl;
      float gi = sums[0  + pl][b] + xi;
      float gf = sums[8  + pl][b] + xf;
      float gg = sums[16 + pl][b] + xgv;
      float go = sums[24 + pl][b] + xo;
      float iv = sigm(gi), fv = sigm(gf), ov = sigm(go);
      c_reg = fv * c_reg + iv * tanh_fast(gg);
      pred[((size_t)(b * UP1 + u)) * PD + p] = ov * tanh_fast(c_reg);
    }
    __threadfence();          // release h writes (agent scope)
    __syncthreads();
    if (tid == 0){
      atomicAdd(&cnt[u], 1u);
      while (__hip_atomic_load(&cnt[u], __ATOMIC_ACQUIRE, __HIP_MEMORY_SCOPE_AGENT) < LSTM_NWG)
        __builtin_amdgcn_s_sleep(2);
    }
    __syncthreads();
    __threadfence();          // acquire: invalidate L1 before reading fresh h
  }
}

// ---------------- K3: fp32 GEMM (A @ W^T + bias) -> bf16 out ----------------
__global__ __launch_bounds__(256) void k_gemm_bias_bf16(
    const float* __restrict__ A, const float* __restrict__ W,
    const float* __restrict__ bias, unsigned short* __restrict__ out, int M)
{
  __shared__ float a_s[16][68];
  __shared__ float b_s[16][68];
  const int m0 = blockIdx.x * 64, n0 = blockIdx.y * 64;
  const int tid = threadIdx.x;
  const int tx = tid & 15, ty = tid >> 4;
  float acc[4][4];
  #pragma unroll
  for (int i2 = 0; i2 < 4; i2++)
    #pragma unroll
    for (int j2 = 0; j2 < 4; j2++) acc[i2][j2] = 0.0f;
  for (int k0 = 0; k0 < 512; k0 += 16){
    int mm = tid >> 2, k4 = (tid & 3) * 4;
    int row = m0 + mm; if (row >= M) row = M - 1;
    float4 av = *(const float4*)(A + (size_t)row * 512 + k0 + k4);
    a_s[k4 + 0][mm] = av.x; a_s[k4 + 1][mm] = av.y;
    a_s[k4 + 2][mm] = av.z; a_s[k4 + 3][mm] = av.w;
    float4 bv = *(const float4*)(W + (size_t)(n0 + mm) * 512 + k0 + k4);
    b_s[k4 + 0][mm] = bv.x; b_s[k4 + 1][mm] = bv.y;
    b_s[k4 + 2][mm] = bv.z; b_s[k4 + 3][mm] = bv.w;
    __syncthreads();
    #pragma unroll
    for (int k = 0; k < 16; k++){
      float4 a4 = *(const float4*)&a_s[k][ty * 4];
      float4 b4 = *(const float4*)&b_s[k][tx * 4];
      float aa[4] = {a4.x, a4.y, a4.z, a4.w};
      float bb[4] = {b4.x, b4.y, b4.z, b4.w};
      #pragma unroll
      for (int i2 = 0; i2 < 4; i2++)
        #pragma unroll
        for (int j2 = 0; j2 < 4; j2++)
          acc[i2][j2] = fmaf(aa[i2], bb[j2], acc[i2][j2]);
    }
    __syncthreads();
  }
  #pragma unroll
  for (int i2 = 0; i2 < 4; i2++){
    int m = m0 + ty * 4 + i2;
    if (m < M){
      #pragma unroll
      for (int j2 = 0; j2 < 4; j2++){
        int n = n0 + tx * 4 + j2;
        out[(size_t)m * 512 + n] = f2bf(acc[i2][j2] + bias[n]);
      }
    }
  }
}

// ---------------- K4: fused joint, A-in-LDS ----------------
// grid (169, 8): blockIdx.x = t-tile*13 + u-tile, blockIdx.y = b.
// Phase 1: A_s[128][512] = tanh(fe+fp) bf16, XOR-swizzled rows (once).
// Phase 2: 8 n-chunks x 16 k-steps, B dbuf via global_load_lds + counted vmcnt.
// Tail: col 1024 via dot with W_joint[1024].
__global__ __launch_bounds__(256, 1) void k_joint2(
    const unsigned short* __restrict__ fe, const unsigned short* __restrict__ fp,
    const unsigned short* __restrict__ wj, const float* __restrict__ bj,
    float* __restrict__ out)
{
  __shared__ unsigned short A_s[128 * 512];   // 128 KB
  __shared__ unsigned short B_s[2][128 * 32]; // 16 KB
  const int tu = blockIdx.x;
  const int b  = blockIdx.y;
  const int tt = tu / 13, ut = tu - tt * 13;
  const int t0 = tt * 16, u0 = ut * 8;
  const int tid = threadIdx.x;
  const int w = tid >> 6, l = tid & 63;
  const int l15 = l & 15, lg = l >> 4;
  const int wr = w >> 1, wc = w & 1;

  // ---- issue B-chunk stage (idx = nt*16 + ks): 2 x global_load_lds(16B) ----
  auto issue = [&](int idx){
    int nt = idx >> 4, ks = idx & 15;
    unsigned short* dbase = (unsigned short*)B_s[idx & 1];
    #pragma unroll
    for (int pass = 0; pass < 2; pass++){
      int s = pass * 256 + tid;          // linear 16B slot
      int rb = s >> 2, cs = s & 3;
      int col8 = cs ^ ((rb >> 1) & 3);   // pre-swizzled source
      const unsigned short* src = wj + (size_t)(nt * 128 + rb) * 512 + ks * 32 + col8 * 8;
      gload_lds16(src, dbase + (size_t)(pass * 256 + w * 64) * 8);
    }
  };

  issue(0);  // prefetch first B chunk under phase 1

  // ---- phase 1: build A_s = tanh(fe + fp), swizzled write ----
  for (int rr = 0; rr < 32; rr++){
    int row = rr * 4 + w;
    int ti = row >> 3, ui = row & 7;
    int t = t0 + ti, uu = u0 + ui;
    ushort8 a = {0,0,0,0,0,0,0,0};
    if (t < TENC && uu < UP1){
      ushort8 f8 = *(const ushort8*)(fe + (size_t)(b * TENC + t) * 512 + l * 8);
      ushort8 p8 = *(const ushort8*)(fp + (size_t)(b * UP1 + uu) * 512 + l * 8);
      #pragma unroll
      for (int j = 0; j < 8; j++)
        a[j] = f2bf(tanh_fast(bf2f(f8[j]) + bf2f(p8[j])));
    }
    int byteo = row * 1024 + ((l * 16) ^ ((row & 7) << 4));
    *(ushort8*)((char*)A_s + byteo) = a;
  }
  __syncthreads();   // drains lgkm + vm (incl. issue(0))

  f32x4 acc[4][4];
  #pragma unroll
  for (int fr = 0; fr < 4; fr++)
    #pragma unroll
    for (int fc = 0; fc < 4; fc++)
      acc[fr][fc] = (f32x4){0.f, 0.f, 0.f, 0.f};

  for (int idx = 0; idx < 128; idx++){
    const int nt = idx >> 4, ks = idx & 15;
    if (idx > 0) __builtin_amdgcn_s_barrier();   // prev compute done
    if (idx + 1 < 128){
      issue(idx + 1);
      asm volatile("s_waitcnt vmcnt(2)" ::: "memory");
    } else {
      asm volatile("s_waitcnt vmcnt(0)" ::: "memory");
    }
    __builtin_amdgcn_s_barrier();                // buffer ready for all waves

    const unsigned short* bb = B_s[idx & 1];
    bf16x8 bfr[4], afr[4];
    #pragma unroll
    for (int fc = 0; fc < 4; fc++){
      int rb = wc * 64 + fc * 16 + l15;
      int byteo = rb * 64 + ((lg ^ ((rb >> 1) & 3)) * 16);
      bfr[fc] = __builtin_bit_cast(bf16x8, *(const ushort8*)((const char*)bb + byteo));
    }
    #pragma unroll
    for (int fr = 0; fr < 4; fr++){
      int ra = wr * 64 + fr * 16 + l15;
      int k8 = ks * 4 + lg;
      int byteo = ra * 1024 + ((k8 * 16) ^ ((ra & 7) << 4));
      afr[fr] = __builtin_bit_cast(bf16x8, *(const ushort8*)((const char*)A_s + byteo));
    }
    #pragma unroll
    for (int fr = 0; fr < 4; fr++)
      #pragma unroll
      for (int fc = 0; fc < 4; fc++)
        acc[fr][fc] = __builtin_amdgcn_mfma_f32_16x16x32_bf16(bfr[fc], afr[fr], acc[fr][fc], 0, 0, 0);

    if (ks == 15){
      // epilogue: C row-side = n (reg dim), col-side = m  -> float4 stores
      #pragma unroll
      for (int fr = 0; fr < 4; fr++){
        int m = wr * 64 + fr * 16 + l15;
        int t = t0 + (m >> 3), uu2 = u0 + (m & 7);
        if (t < TENC && uu2 < UP1){
          float* orow = out + ((size_t)(b * TENC + t) * UP1 + uu2) * VP1;
          #pragma unroll
          for (int fc = 0; fc < 4; fc++){
            int nb = nt * 128 + wc * 64 + fc * 16 + lg * 4;
            float4 bv = *(const float4*)(bj + nb);
            f32x4 v = acc[fr][fc];
            float4 st = {v[0] + bv.x, v[1] + bv.y, v[2] + bv.z, v[3] + bv.w};
            *(float4*)(orow + nb) = st;
          }
        }
        #pragma unroll
        for (int fc = 0; fc < 4; fc++)
          acc[fr][fc] = (f32x4){0.f, 0.f, 0.f, 0.f};
      }
    }
  }

  // ---- tail: column 1024 (blank logit) ----
  {
    int row = tid >> 1, half = tid & 1;
    float s = 0.0f;
    const unsigned short* w1 = wj + (size_t)1024 * 512;
    #pragma unroll 8
    for (int q = 0; q < 32; q++){
      int k8 = half * 32 + q;
      int byteo = row * 1024 + ((k8 * 16) ^ ((row & 7) << 4));
      ushort8 a8 = *(const ushort8*)((const char*)A_s + byteo);
      ushort8 w8 = *(const ushort8*)(w1 + k8 * 8);
      #pragma unroll
      for (int j = 0; j < 8; j++)
        s += bf2f(a8[j]) * bf2f(w8[j]);
    }
    s += __shfl_xor(s, 1);
    if (half == 0){
      int t = t0 + (row >> 3), uu = u0 + (row & 7);
      if (t < TENC && uu < UP1)
        out[((size_t)(b * TENC + t) * UP1 + uu) * VP1 + 1024] = s + bj[1024];
    }
  }
}

extern "C" void kernel_launch(void* const* d_in, const int* in_sizes, int n_in,
                              void* d_out, int out_size, void* d_ws, size_t ws_size,
                              hipStream_t stream) {
  const float* enc_out = (const float*)d_in[0];
  const int*   targets = (const int*)d_in[1];
  const float* emb     = (const float*)d_in[3];
  const float* W_ih    = (const float*)d_in[4];
  const float* W_hh    = (const float*)d_in[5];
  const float* b_ih    = (const float*)d_in[6];
  const float* b_hh    = (const float*)d_in[7];
  const float* W_enc   = (const float*)d_in[8];
  const float* b_enc   = (const float*)d_in[9];
  const float* W_pred  = (const float*)d_in[10];
  const float* b_pred  = (const float*)d_in[11];
  const float* W_joint = (const float*)d_in[12];
  const float* b_joint = (const float*)d_in[13];
  float* out = (float*)d_out;

  char* ws = (char*)d_ws;
  float* xg            = (float*)(ws + 0);                  // 8*101*2048*4 = 6,619,136
  float* pred          = (float*)(ws + 6619136);            // 8*101*512*4  = 1,654,784
  unsigned short* feb  = (unsigned short*)(ws + 8273920);   // 1600*512*2   = 1,638,400
  unsigned short* fpb  = (unsigned short*)(ws + 9912320);   // 808*512*2    =   827,392
  unsigned short* wjb  = (unsigned short*)(ws + 10739712);  // 1025*512*2   = 1,049,600
  unsigned int*   cnt  = (unsigned int*)(ws + 11789312);    // 101*4
  // total ~11.8 MB

  hipMemsetAsync(cnt, 0, UP1 * sizeof(unsigned int), stream);
  hipLaunchKernelGGL(k_cvt_bf16, dim3((VP1 * 512 + 255) / 256), dim3(256), 0, stream,
                     W_joint, wjb, VP1 * 512);
  hipLaunchKernelGGL(k_xgate, dim3(404), dim3(256), 0, stream,
                     emb, targets, W_ih, b_ih, b_hh, xg);
  hipLaunchKernelGGL(k_gemm_bias_bf16, dim3(25, 8), dim3(256), 0, stream,
                     enc_out, W_enc, b_enc, feb, 1600);
  hipLaunchKernelGGL(k_lstm_all, dim3(LSTM_NWG), dim3(256), 0, stream,
                     xg, W_hh, pred, cnt);
  hipLaunchKernelGGL(k_gemm_bias_bf16, dim3(13, 8), dim3(256), 0, stream,
                     pred, W_pred, b_pred, fpb, 808);
  hipLaunchKernelGGL(k_joint2, dim3(169, 8), dim3(256), 0, stream,
                     feb, fpb, wjb, b_joint, out);
}

// Round 3
// 1003.823 us; speedup vs baseline: 2.1343x; 2.1343x over previous
//
#include <hip/hip_runtime.h>
#include <stdint.h>
#include <stddef.h>

#define BB 8
#define TENC 200
#define UU 100
#define UP1 101
#define VP1 1025
#define ED 128
#define PD 512
#define LSTM_NWG 64

typedef __attribute__((ext_vector_type(8))) unsigned short ushort8;
typedef __attribute__((ext_vector_type(8))) __bf16 bf16x8;
typedef __attribute__((ext_vector_type(4))) float f32x4;

__device__ __forceinline__ float bf2f(unsigned short u){
  unsigned int x = ((unsigned int)u) << 16;
  return __builtin_bit_cast(float, x);
}
__device__ __forceinline__ unsigned short f2bf(float f){
  unsigned int x = __builtin_bit_cast(unsigned int, f);
  unsigned int r = (x + 0x7fffu + ((x >> 16) & 1u)) >> 16;
  return (unsigned short)r;
}
__device__ __forceinline__ float tanh_fast(float x){
  float e = __expf(2.0f * x);
  return 1.0f - 2.0f / (e + 1.0f);
}
__device__ __forceinline__ float sigm(float x){
  return 1.0f / (1.0f + __expf(-x));
}
__device__ __forceinline__ void gload_lds16(const unsigned short* gsrc, unsigned short* ldst){
  __builtin_amdgcn_global_load_lds((const __attribute__((address_space(1))) void*)gsrc,
                                   (__attribute__((address_space(3))) void*)ldst, 16, 0, 0);
}

// ---------------- fp32 -> bf16 convert (W_joint) ----------------
__global__ __launch_bounds__(256) void k_cvt_bf16(const float* __restrict__ src,
                                                  unsigned short* __restrict__ dst, int n){
  int i = blockIdx.x * 256 + threadIdx.x;
  if (i < n) dst[i] = f2bf(src[i]);
}

// ---------------- K1: embedding + x-part of LSTM gates ----------------
__global__ __launch_bounds__(256) void k_xgate(
    const float* __restrict__ emb, const int* __restrict__ targets,
    const float* __restrict__ W_ih, const float* __restrict__ b_ih,
    const float* __restrict__ b_hh, float* __restrict__ xg)
{
  __shared__ float e_s[BB * ED];
  const int u  = blockIdx.x >> 2;
  const int jq = blockIdx.x & 3;
  const int tid = threadIdx.x;
  for (int idx = tid; idx < BB * ED; idx += 256){
    int b = idx >> 7, e = idx & 127;
    int tok = (u == 0) ? 1024 : targets[b * UU + (u - 1)];
    e_s[idx] = emb[(size_t)tok * ED + e];
  }
  __syncthreads();
  float acc[2][BB];
  #pragma unroll
  for (int r = 0; r < 2; r++)
    #pragma unroll
    for (int b = 0; b < BB; b++) acc[r][b] = 0.0f;
  const int j0 = jq * 512 + tid;
  const float* w0p = W_ih + (size_t)j0 * ED;
  const float* w1p = W_ih + (size_t)(j0 + 256) * ED;
  for (int e = 0; e < ED; e++){
    float w0 = w0p[e], w1 = w1p[e];
    #pragma unroll
    for (int b = 0; b < BB; b++){
      float ev = e_s[b * ED + e];
      acc[0][b] = fmaf(ev, w0, acc[0][b]);
      acc[1][b] = fmaf(ev, w1, acc[1][b]);
    }
  }
  #pragma unroll
  for (int r = 0; r < 2; r++){
    int j = j0 + r * 256;
    float bias = b_ih[j] + b_hh[j];
    #pragma unroll
    for (int b = 0; b < BB; b++)
      xg[((size_t)b * UP1 + u) * 2048 + j] = acc[r][b] + bias;
  }
}

// ---------------- K2: persistent LSTM, relaxed-atomic coherence ----------------
// 64 WGs x 256 thr. WG wg owns hidden units [8*wg, 8*wg+8) -> 32 gate rows.
// h exchanged via relaxed agent-scope atomics (LLC-coherent, no cache flushes).
// Barrier: s_waitcnt vmcnt(0) (in-order retirement => h stores done) + relaxed
// fetch_add; readers poll relaxed. cnt[] zeroed by memsetAsync each launch.
__global__ __launch_bounds__(256) void k_lstm_all(
    const float* __restrict__ xg, const float* __restrict__ W_hh,
    float* __restrict__ pred, unsigned int* __restrict__ cnt)
{
  __shared__ float h_s[8][520];
  __shared__ float red[32 * 257];
  __shared__ float gates_s[32][9];
  const int tid = threadIdx.x;
  const int wg  = blockIdx.x;
  const int p0  = wg * 8;
  const int jg = tid >> 5, kc = tid & 31;
  const float* wrow[4];
  #pragma unroll
  for (int r = 0; r < 4; r++){
    int jl = jg * 4 + r;                       // 0..31, jl = g*8 + pl
    int grow = (jl >> 3) * PD + p0 + (jl & 7); // W_hh row
    wrow[r] = W_hh + (size_t)grow * PD;
  }
  float c_reg = 0.0f;                          // cell state (tid<64 threads)
  for (int u = 0; u < UP1; u++){
    // x-gate prefetch (independent of h)
    float xi = 0.f, xf = 0.f, xgv = 0.f, xo = 0.f;
    if (tid < 64){
      int pl = tid >> 3, b = tid & 7;
      const float* xr = xg + ((size_t)(b * UP1 + u)) * 2048;
      int p = p0 + pl;
      xi = xr[p]; xf = xr[512 + p]; xgv = xr[1024 + p]; xo = xr[1536 + p];
    }
    if (u > 0){
      if (tid == 0){
        while (__hip_atomic_load(&cnt[u - 1], __ATOMIC_RELAXED, __HIP_MEMORY_SCOPE_AGENT) < LSTM_NWG)
          __builtin_amdgcn_s_sleep(8);
      }
      __syncthreads();
      // coherent h load, batched: 16 loads in flight, then LDS writes
      float tmp[16];
      #pragma unroll
      for (int j = 0; j < 16; j++){
        int i = tid + 256 * j;
        int b2 = i >> 9, k = i & 511;
        tmp[j] = __hip_atomic_load(pred + ((size_t)(b2 * UP1 + (u - 1))) * PD + k,
                                   __ATOMIC_RELAXED, __HIP_MEMORY_SCOPE_AGENT);
      }
      #pragma unroll
      for (int j = 0; j < 16; j++){
        int i = tid + 256 * j;
        h_s[i >> 9][i & 511] = tmp[j];
      }
    } else {
      for (int i = tid; i < 8 * PD; i += 256) h_s[i >> 9][i & 511] = 0.0f;
    }
    __syncthreads();
    float acc[4][BB];
    #pragma unroll
    for (int r = 0; r < 4; r++)
      #pragma unroll
      for (int b = 0; b < BB; b++) acc[r][b] = 0.0f;
    for (int i = 0; i < 16; i++){
      int k = kc + 32 * i;
      float hv[BB];
      #pragma unroll
      for (int b = 0; b < BB; b++) hv[b] = h_s[b][k];
      #pragma unroll
      for (int r = 0; r < 4; r++){
        float wv = wrow[r][k];
        #pragma unroll
        for (int b = 0; b < BB; b++) acc[r][b] = fmaf(hv[b], wv, acc[r][b]);
      }
    }
    #pragma unroll
    for (int r = 0; r < 4; r++)
      #pragma unroll
      for (int b = 0; b < BB; b++)
        red[kc * 257 + jg * 32 + r * 8 + b] = acc[r][b];
    __syncthreads();
    {
      int jl = tid >> 3, b = tid & 7;
      float s = 0.0f;
      #pragma unroll
      for (int kk = 0; kk < 32; kk++)
        s += red[kk * 257 + (jl >> 2) * 32 + (jl & 3) * 8 + b];
      gates_s[jl][b] = s;
    }
    __syncthreads();
    if (tid < 64){
      int pl = tid >> 3, b = tid & 7;
      int p = p0 + pl;
      float gi = gates_s[0  + pl][b] + xi;
      float gf = gates_s[8  + pl][b] + xf;
      float gg = gates_s[16 + pl][b] + xgv;
      float go = gates_s[24 + pl][b] + xo;
      float iv = sigm(gi), fv = sigm(gf), ov = sigm(go);
      c_reg = fv * c_reg + iv * tanh_fast(gg);
      float hval = ov * tanh_fast(c_reg);
      __hip_atomic_store(pred + ((size_t)(b * UP1 + u)) * PD + p, hval,
                         __ATOMIC_RELAXED, __HIP_MEMORY_SCOPE_AGENT);
    }
    if (u < UP1 - 1){
      if (tid == 0){
        asm volatile("s_waitcnt vmcnt(0)" ::: "memory"); // h stores (wave 0) complete
        __hip_atomic_fetch_add(&cnt[u], 1u, __ATOMIC_RELAXED, __HIP_MEMORY_SCOPE_AGENT);
      }
    }
    // non-tid0 threads run ahead; they block at next iteration's poll-sync,
    // and h_s is only overwritten after that sync.
  }
}

// ---------------- K3: fp32 GEMM (A @ W^T + bias) -> bf16 out ----------------
__global__ __launch_bounds__(256) void k_gemm_bias_bf16(
    const float* __restrict__ A, const float* __restrict__ W,
    const float* __restrict__ bias, unsigned short* __restrict__ out, int M)
{
  __shared__ float a_s[16][68];
  __shared__ float b_s[16][68];
  const int m0 = blockIdx.x * 64, n0 = blockIdx.y * 64;
  const int tid = threadIdx.x;
  const int tx = tid & 15, ty = tid >> 4;
  float acc[4][4];
  #pragma unroll
  for (int i2 = 0; i2 < 4; i2++)
    #pragma unroll
    for (int j2 = 0; j2 < 4; j2++) acc[i2][j2] = 0.0f;
  for (int k0 = 0; k0 < 512; k0 += 16){
    int mm = tid >> 2, k4 = (tid & 3) * 4;
    int row = m0 + mm; if (row >= M) row = M - 1;
    float4 av = *(const float4*)(A + (size_t)row * 512 + k0 + k4);
    a_s[k4 + 0][mm] = av.x; a_s[k4 + 1][mm] = av.y;
    a_s[k4 + 2][mm] = av.z; a_s[k4 + 3][mm] = av.w;
    float4 bv = *(const float4*)(W + (size_t)(n0 + mm) * 512 + k0 + k4);
    b_s[k4 + 0][mm] = bv.x; b_s[k4 + 1][mm] = bv.y;
    b_s[k4 + 2][mm] = bv.z; b_s[k4 + 3][mm] = bv.w;
    __syncthreads();
    #pragma unroll
    for (int k = 0; k < 16; k++){
      float4 a4 = *(const float4*)&a_s[k][ty * 4];
      float4 b4 = *(const float4*)&b_s[k][tx * 4];
      float aa[4] = {a4.x, a4.y, a4.z, a4.w};
      float bb[4] = {b4.x, b4.y, b4.z, b4.w};
      #pragma unroll
      for (int i2 = 0; i2 < 4; i2++)
        #pragma unroll
        for (int j2 = 0; j2 < 4; j2++)
          acc[i2][j2] = fmaf(aa[i2], bb[j2], acc[i2][j2]);
    }
    __syncthreads();
  }
  #pragma unroll
  for (int i2 = 0; i2 < 4; i2++){
    int m = m0 + ty * 4 + i2;
    if (m < M){
      #pragma unroll
      for (int j2 = 0; j2 < 4; j2++){
        int n = n0 + tx * 4 + j2;
        out[(size_t)m * 512 + n] = f2bf(acc[i2][j2] + bias[n]);
      }
    }
  }
}

// ---------------- K4: fused joint, A-in-LDS, 8 waves, 3-buf B, 1 barrier/iter ----
__global__ __launch_bounds__(512, 1) void k_joint3(
    const unsigned short* __restrict__ fe, const unsigned short* __restrict__ fp,
    const unsigned short* __restrict__ wj, const float* __restrict__ bj,
    float* __restrict__ out)
{
  __shared__ unsigned short A_s[128 * 512];     // 128 KB, swizzled
  __shared__ unsigned short B_s[3][128 * 32];   // 24 KB, 3-buffer rotation
  const int tu = blockIdx.x;
  const int b  = blockIdx.y;
  const int tt = tu / 13, ut = tu - tt * 13;
  const int t0 = tt * 16, u0 = ut * 8;
  const int tid = threadIdx.x;
  const int w = tid >> 6, l = tid & 63;
  const int l15 = l & 15, lg = l >> 4;
  const int wr = w >> 1, wc = w & 1;

  // stage one B chunk (idx = nt*16 + ks): 128 rows x 32 bf16 = 8KB = 512x16B
  auto issue = [&](int idx){
    int nt = idx >> 4, ks = idx & 15;
    int rb = tid >> 2, cs = tid & 3;
    int col8 = cs ^ ((rb >> 1) & 3);           // pre-swizzled source
    const unsigned short* src = wj + (size_t)(nt * 128 + rb) * 512 + ks * 32 + col8 * 8;
    gload_lds16(src, (unsigned short*)B_s[idx % 3] + (size_t)(w * 64) * 8);
  };

  issue(0);   // prefetch under A-build

  // ---- phase 1: A_s = tanh(fe + fp) bf16, swizzled, built ONCE ----
  for (int rr = 0; rr < 16; rr++){
    int row = rr * 8 + w;
    int ti = row >> 3, ui = row & 7;
    int t = t0 + ti, uu = u0 + ui;
    ushort8 a = {0,0,0,0,0,0,0,0};
    if (t < TENC && uu < UP1){
      ushort8 f8 = *(const ushort8*)(fe + (size_t)(b * TENC + t) * 512 + l * 8);
      ushort8 p8 = *(const ushort8*)(fp + (size_t)(b * UP1 + uu) * 512 + l * 8);
      #pragma unroll
      for (int j = 0; j < 8; j++)
        a[j] = f2bf(tanh_fast(bf2f(f8[j]) + bf2f(p8[j])));
    }
    int byteo = row * 1024 + ((l * 16) ^ ((row & 7) << 4));
    *(ushort8*)((char*)A_s + byteo) = a;
  }
  __syncthreads();   // drains lgkm + vm (incl. issue(0))

  f32x4 acc[2][4];
  #pragma unroll
  for (int fr = 0; fr < 2; fr++)
    #pragma unroll
    for (int fc = 0; fc < 4; fc++)
      acc[fr][fc] = (f32x4){0.f, 0.f, 0.f, 0.f};

  for (int idx = 0; idx < 128; idx++){
    const int nt = idx >> 4, ks = idx & 15;
    if (idx + 1 < 128){
      issue(idx + 1);                                   // writes buf (idx+1)%3; last read 2 iters ago
      asm volatile("s_waitcnt vmcnt(1)" ::: "memory");  // in-order: idx's load (and stores) done
    } else {
      asm volatile("s_waitcnt vmcnt(0)" ::: "memory");
    }
    __builtin_amdgcn_s_barrier();                       // all waves' loads landed; prev compute done

    const unsigned short* bb = (const unsigned short*)B_s[idx % 3];
    bf16x8 bfr[4], afr[2];
    #pragma unroll
    for (int fc = 0; fc < 4; fc++){
      int rb = wc * 64 + fc * 16 + l15;
      int byteo = rb * 64 + ((lg ^ ((rb >> 1) & 3)) * 16);
      bfr[fc] = __builtin_bit_cast(bf16x8, *(const ushort8*)((const char*)bb + byteo));
    }
    #pragma unroll
    for (int fr = 0; fr < 2; fr++){
      int ra = wr * 32 + fr * 16 + l15;
      int k8 = ks * 4 + lg;
      int byteo = ra * 1024 + ((k8 * 16) ^ ((ra & 7) << 4));
      afr[fr] = __builtin_bit_cast(bf16x8, *(const ushort8*)((const char*)A_s + byteo));
    }
    #pragma unroll
    for (int fr = 0; fr < 2; fr++)
      #pragma unroll
      for (int fc = 0; fc < 4; fc++)
        acc[fr][fc] = __builtin_amdgcn_mfma_f32_16x16x32_bf16(bfr[fc], afr[fr], acc[fr][fc], 0, 0, 0);

    if (ks == 15){
      // epilogue: C reg-dim = n, lane l15 = m  -> contiguous float4 stores
      #pragma unroll
      for (int fr = 0; fr < 2; fr++){
        int m = wr * 32 + fr * 16 + l15;
        int t = t0 + (m >> 3), uu2 = u0 + (m & 7);
        if (t < TENC && uu2 < UP1){
          float* orow = out + ((size_t)(b * TENC + t) * UP1 + uu2) * VP1;
          #pragma unroll
          for (int fc = 0; fc < 4; fc++){
            int nb = nt * 128 + wc * 64 + fc * 16 + lg * 4;
            float4 bv = *(const float4*)(bj + nb);
            f32x4 v = acc[fr][fc];
            float4 st = {v[0] + bv.x, v[1] + bv.y, v[2] + bv.z, v[3] + bv.w};
            *(float4*)(orow + nb) = st;
          }
        }
        #pragma unroll
        for (int fc = 0; fc < 4; fc++)
          acc[fr][fc] = (f32x4){0.f, 0.f, 0.f, 0.f};
      }
    }
  }

  // ---- tail: column 1024 (blank logit) ----
  {
    int row = tid >> 2, q = tid & 3;
    float s = 0.0f;
    const unsigned short* w1 = wj + (size_t)1024 * 512;
    #pragma unroll 4
    for (int j = 0; j < 16; j++){
      int k8 = q * 16 + j;
      int byteo = row * 1024 + ((k8 * 16) ^ ((row & 7) << 4));
      ushort8 a8 = *(const ushort8*)((const char*)A_s + byteo);
      ushort8 w8 = *(const ushort8*)(w1 + k8 * 8);
      #pragma unroll
      for (int jj = 0; jj < 8; jj++)
        s += bf2f(a8[jj]) * bf2f(w8[jj]);
    }
    s += __shfl_xor(s, 1);
    s += __shfl_xor(s, 2);
    if (q == 0){
      int t = t0 + (row >> 3), uu = u0 + (row & 7);
      if (t < TENC && uu < UP1)
        out[((size_t)(b * TENC + t) * UP1 + uu) * VP1 + 1024] = s + bj[1024];
    }
  }
}

extern "C" void kernel_launch(void* const* d_in, const int* in_sizes, int n_in,
                              void* d_out, int out_size, void* d_ws, size_t ws_size,
                              hipStream_t stream) {
  const float* enc_out = (const float*)d_in[0];
  const int*   targets = (const int*)d_in[1];
  const float* emb     = (const float*)d_in[3];
  const float* W_ih    = (const float*)d_in[4];
  const float* W_hh    = (const float*)d_in[5];
  const float* b_ih    = (const float*)d_in[6];
  const float* b_hh    = (const float*)d_in[7];
  const float* W_enc   = (const float*)d_in[8];
  const float* b_enc   = (const float*)d_in[9];
  const float* W_pred  = (const float*)d_in[10];
  const float* b_pred  = (const float*)d_in[11];
  const float* W_joint = (const float*)d_in[12];
  const float* b_joint = (const float*)d_in[13];
  float* out = (float*)d_out;

  char* ws = (char*)d_ws;
  float* xg            = (float*)(ws + 0);                  // 6,619,136 B
  float* pred          = (float*)(ws + 6619136);            // 1,654,784 B
  unsigned short* feb  = (unsigned short*)(ws + 8273920);   // 1,638,400 B
  unsigned short* fpb  = (unsigned short*)(ws + 9912320);   //   827,392 B
  unsigned short* wjb  = (unsigned short*)(ws + 10739712);  // 1,049,600 B
  unsigned int*   cnt  = (unsigned int*)(ws + 11789312);    // 404 B

  hipMemsetAsync(cnt, 0, UP1 * sizeof(unsigned int), stream);
  hipLaunchKernelGGL(k_cvt_bf16, dim3((VP1 * 512 + 255) / 256), dim3(256), 0, stream,
                     W_joint, wjb, VP1 * 512);
  hipLaunchKernelGGL(k_xgate, dim3(404), dim3(256), 0, stream,
                     emb, targets, W_ih, b_ih, b_hh, xg);
  hipLaunchKernelGGL(k_gemm_bias_bf16, dim3(25, 8), dim3(256), 0, stream,
                     enc_out, W_enc, b_enc, feb, 1600);
  hipLaunchKernelGGL(k_lstm_all, dim3(LSTM_NWG), dim3(256), 0, stream,
                     xg, W_hh, pred, cnt);
  hipLaunchKernelGGL(k_gemm_bias_bf16, dim3(13, 8), dim3(256), 0, stream,
                     pred, W_pred, b_pred, fpb, 808);
  hipLaunchKernelGGL(k_joint3, dim3(169, 8), dim3(512), 0, stream,
                     feb, fpb, wjb, b_joint, out);
}